// Round 1
// baseline (1113.280 us; speedup 1.0000x reference)
//
#include <hip/hip_runtime.h>
#include <hip/hip_bf16.h>

typedef __attribute__((ext_vector_type(8))) short bf16x8;
typedef __attribute__((ext_vector_type(4))) float f32x4;
typedef __attribute__((ext_vector_type(4))) unsigned short u16x4;

static __device__ __forceinline__ unsigned short f2bf(float f) {
    union { float f; unsigned u; } v; v.f = f;
    unsigned r = v.u + 0x7fffu + ((v.u >> 16) & 1u);
    return (unsigned short)(r >> 16);
}

// ---------------------------------------------------------------------------
// Weight conversion: fp32 -> bf16, transposed (N-major) and K-step-blocked:
//   dst[(k>>5)*(N*32) + n*32 + (k&31)]
// WcT:  N=256, K=512 (rows 0..255 = W_vv, 256..511 = W_vc)
// bW1T: N=512, K=512
// uW1T: N=512, K=256
// ---------------------------------------------------------------------------
__global__ __launch_bounds__(256) void conv_weights(
    const float* __restrict__ Wvv, const float* __restrict__ Wvc,
    const float* __restrict__ bW1, const float* __restrict__ uW1,
    unsigned short* __restrict__ WcT, unsigned short* __restrict__ bW1T,
    unsigned short* __restrict__ uW1T)
{
    int idx = blockIdx.x * 256 + threadIdx.x;
    if (idx < 131072) {
        int n = idx >> 9, k = idx & 511;
        float s = (k < 256) ? Wvv[k * 256 + n] : Wvc[(k - 256) * 256 + n];
        WcT[(k >> 5) * 8192 + n * 32 + (k & 31)] = f2bf(s);
    } else if (idx < 131072 + 262144) {
        int t = idx - 131072;
        int n = t >> 9, k = t & 511;
        bW1T[(k >> 5) * 16384 + n * 32 + (k & 31)] = f2bf(bW1[k * 512 + n]);
    } else if (idx < 131072 + 262144 + 131072) {
        int t = idx - 393216;
        int n = t >> 8, k = t & 255;
        uW1T[(k >> 5) * 16384 + n * 32 + (k & 31)] = f2bf(uW1[k * 512 + n]);
    }
}

// ---------------------------------------------------------------------------
// ha = relu(ha_prev @ W_vv + c_atom @ W_vc); ha[0]=0
// Writes ha as bf16; atomically accumulates hm[mol_id[row]] += ha_row (fp32).
// BM=64, N=256, K=512. 4 waves, each owns a 64x64 tile (4x4 MFMA frags).
// ---------------------------------------------------------------------------
__global__ __launch_bounds__(256) void ha_kernel(
    const float* __restrict__ ha_prev, const float* __restrict__ c_atom,
    const unsigned short* __restrict__ WcT, const int* __restrict__ mol_id,
    unsigned short* __restrict__ haB, float* __restrict__ hm, int NA)
{
    __shared__ unsigned short Asm[64][40];   // 32 bf16 + 8 pad (row stride 80B)
    __shared__ unsigned short Bsm[256][40];  // [n][k] 32 bf16 + pad

    const int tid = threadIdx.x;
    const int wv = tid >> 6, lane = tid & 63;
    const int c15 = lane & 15, kq = lane >> 4;
    const int m0 = blockIdx.x * 64;

    f32x4 acc[4][4];
#pragma unroll
    for (int m = 0; m < 4; ++m)
#pragma unroll
        for (int n = 0; n < 4; ++n) acc[m][n] = (f32x4){0.f, 0.f, 0.f, 0.f};

    for (int ks = 0; ks < 16; ++ks) {
        __syncthreads();
        const float* src = (ks < 8) ? ha_prev : c_atom;
        const int kb = (ks * 32) & 255;
#pragma unroll
        for (int i = 0; i < 2; ++i) {
            int f = i * 256 + tid;          // 512 chunks of 16B fp32
            int r = f >> 3, p = f & 7;
            int row = m0 + r;
            f32x4 v = (f32x4){0.f, 0.f, 0.f, 0.f};
            if (row < NA) v = *(const f32x4*)(src + (size_t)row * 256 + kb + p * 4);
            u16x4 u = { f2bf(v[0]), f2bf(v[1]), f2bf(v[2]), f2bf(v[3]) };
            *(u16x4*)&Asm[r][p * 4] = u;
        }
        const unsigned short* bs = WcT + ks * 8192;
#pragma unroll
        for (int i = 0; i < 4; ++i) {
            int f = i * 256 + tid;          // 1024 chunks of 16B
            int n = f >> 2, p = f & 3;
            *(bf16x8*)&Bsm[n][p * 8] = *(const bf16x8*)(bs + f * 8);
        }
        __syncthreads();
        bf16x8 aF[4], bF[4];
#pragma unroll
        for (int m = 0; m < 4; ++m) aF[m] = *(const bf16x8*)&Asm[m * 16 + c15][kq * 8];
#pragma unroll
        for (int n = 0; n < 4; ++n) bF[n] = *(const bf16x8*)&Bsm[wv * 64 + n * 16 + c15][kq * 8];
#pragma unroll
        for (int m = 0; m < 4; ++m)
#pragma unroll
            for (int n = 0; n < 4; ++n)
                acc[m][n] = __builtin_amdgcn_mfma_f32_16x16x32_bf16(aF[m], bF[n], acc[m][n], 0, 0, 0);
    }

    // epilogue: relu, zero row 0, store bf16, atomic hm accumulation
    const int colb = wv * 64;
#pragma unroll
    for (int m = 0; m < 4; ++m) {
#pragma unroll
        for (int reg = 0; reg < 4; ++reg) {
            int grow = m0 + m * 16 + kq * 4 + reg;
            if (grow >= NA) continue;
            int mol = mol_id[grow];
            bool z = (grow == 0);
#pragma unroll
            for (int n = 0; n < 4; ++n) {
                int col = colb + n * 16 + c15;
                float v = fmaxf(acc[m][n][reg], 0.f);
                if (z) v = 0.f;
                haB[(size_t)grow * 256 + col] = f2bf(v);
                if (!z) atomicAdd(&hm[mol * 256 + col], v);
            }
        }
    }
}

// ---------------------------------------------------------------------------
// bond_logits = relu([ha[b0]|ha[b1]] @ W1 + b1) @ W2 + b2   (fused 2-layer MLP)
// BM=64 bonds, N=512 hidden, K=512. 8 waves x 64 cols.
// ---------------------------------------------------------------------------
__global__ __launch_bounds__(512) void bond_kernel(
    const unsigned short* __restrict__ haB, const int* __restrict__ bidx,
    const unsigned short* __restrict__ bW1T,
    const float* __restrict__ b1, const float* __restrict__ W2,
    const float* __restrict__ b2, float* __restrict__ outB, int NB)
{
    __shared__ unsigned short Asm[64][520];  // 512 bf16 + 8 pad (1040B rows)
    __shared__ unsigned short Bsm[512][40];
    __shared__ float obuf[64][5];

    const int tid = threadIdx.x;
    const int wv = tid >> 6, lane = tid & 63;
    const int c15 = lane & 15, kq = lane >> 4;
    const int b0 = blockIdx.x * 64;

    if (tid < 320) ((float*)obuf)[tid] = 0.f;

    // gather A: 64 bonds x 1KB (two 512B ha rows each)
#pragma unroll
    for (int i = 0; i < 8; ++i) {
        int f = i * 512 + tid;              // 4096 chunks of 16B
        int r = f >> 6, ch = f & 63;
        int grow = b0 + r;
        bf16x8 v = {0, 0, 0, 0, 0, 0, 0, 0};
        if (grow < NB) {
            int ep = ch >> 5, o = ch & 31;
            int aidx = bidx[grow * 2 + ep];
            v = *(const bf16x8*)(haB + (size_t)aidx * 256 + o * 8);
        }
        *(bf16x8*)&Asm[r][ch * 8] = v;
    }

    f32x4 acc[4][4];
#pragma unroll
    for (int m = 0; m < 4; ++m)
#pragma unroll
        for (int n = 0; n < 4; ++n) acc[m][n] = (f32x4){0.f, 0.f, 0.f, 0.f};

    for (int ks = 0; ks < 16; ++ks) {
        __syncthreads();
        const unsigned short* bs = bW1T + ks * 16384;
#pragma unroll
        for (int i = 0; i < 4; ++i) {
            int f = i * 512 + tid;          // 2048 chunks of 16B
            int n = f >> 2, p = f & 3;
            *(bf16x8*)&Bsm[n][p * 8] = *(const bf16x8*)(bs + f * 8);
        }
        __syncthreads();
        bf16x8 aF[4], bF[4];
#pragma unroll
        for (int m = 0; m < 4; ++m) aF[m] = *(const bf16x8*)&Asm[m * 16 + c15][ks * 32 + kq * 8];
#pragma unroll
        for (int n = 0; n < 4; ++n) bF[n] = *(const bf16x8*)&Bsm[wv * 64 + n * 16 + c15][kq * 8];
#pragma unroll
        for (int m = 0; m < 4; ++m)
#pragma unroll
            for (int n = 0; n < 4; ++n)
                acc[m][n] = __builtin_amdgcn_mfma_f32_16x16x32_bf16(aF[m], bF[n], acc[m][n], 0, 0, 0);
    }

    // fused layer 2: per-row dot with W2 over this wave's 64 cols, then reduce
    const int colb = wv * 64;
    float b1c[4], w2c[4][5];
#pragma unroll
    for (int n = 0; n < 4; ++n) {
        int col = colb + n * 16 + c15;
        b1c[n] = b1[col];
#pragma unroll
        for (int j = 0; j < 5; ++j) w2c[n][j] = W2[col * 5 + j];
    }
#pragma unroll
    for (int m = 0; m < 4; ++m) {
#pragma unroll
        for (int reg = 0; reg < 4; ++reg) {
            float s[5] = {0.f, 0.f, 0.f, 0.f, 0.f};
#pragma unroll
            for (int n = 0; n < 4; ++n) {
                float p = fmaxf(acc[m][n][reg] + b1c[n], 0.f);
#pragma unroll
                for (int j = 0; j < 5; ++j) s[j] += p * w2c[n][j];
            }
#pragma unroll
            for (int off = 1; off < 16; off <<= 1)
#pragma unroll
                for (int j = 0; j < 5; ++j) s[j] += __shfl_xor(s[j], off, 64);
            if (c15 == 0) {
                int rl = m * 16 + kq * 4 + reg;
#pragma unroll
                for (int j = 0; j < 5; ++j) atomicAdd(&obuf[rl][j], s[j]);
            }
        }
    }
    __syncthreads();
    {
        int r = tid >> 3, j = tid & 7;
        if (j < 5) {
            int grow = b0 + r;
            if (grow < NB) outB[(size_t)grow * 5 + j] = obuf[r][j] + b2[j];
        }
    }
}

// ---------------------------------------------------------------------------
// uni_logits = relu(ha @ W1 + b1) @ W2 + b2   (fused 2-layer MLP, out dim 1)
// BM=64 atoms, N=512 hidden, K=256. 8 waves x 64 cols.
// ---------------------------------------------------------------------------
__global__ __launch_bounds__(512) void uni_kernel(
    const unsigned short* __restrict__ haB, const unsigned short* __restrict__ uW1T,
    const float* __restrict__ b1, const float* __restrict__ W2,
    const float* __restrict__ b2, float* __restrict__ outU, int NA)
{
    __shared__ unsigned short Asm[64][264];  // 256 bf16 + 8 pad (528B rows)
    __shared__ unsigned short Bsm[512][40];
    __shared__ float obuf[64];

    const int tid = threadIdx.x;
    const int wv = tid >> 6, lane = tid & 63;
    const int c15 = lane & 15, kq = lane >> 4;
    const int a0 = blockIdx.x * 64;

    if (tid < 64) obuf[tid] = 0.f;

#pragma unroll
    for (int i = 0; i < 4; ++i) {
        int f = i * 512 + tid;              // 2048 chunks of 16B
        int r = f >> 5, c = f & 31;
        int grow = a0 + r;
        bf16x8 v = {0, 0, 0, 0, 0, 0, 0, 0};
        if (grow < NA) v = *(const bf16x8*)(haB + (size_t)grow * 256 + c * 8);
        *(bf16x8*)&Asm[r][c * 8] = v;
    }

    f32x4 acc[4][4];
#pragma unroll
    for (int m = 0; m < 4; ++m)
#pragma unroll
        for (int n = 0; n < 4; ++n) acc[m][n] = (f32x4){0.f, 0.f, 0.f, 0.f};

    for (int ks = 0; ks < 8; ++ks) {
        __syncthreads();
        const unsigned short* bs = uW1T + ks * 16384;
#pragma unroll
        for (int i = 0; i < 4; ++i) {
            int f = i * 512 + tid;
            int n = f >> 2, p = f & 3;
            *(bf16x8*)&Bsm[n][p * 8] = *(const bf16x8*)(bs + f * 8);
        }
        __syncthreads();
        bf16x8 aF[4], bF[4];
#pragma unroll
        for (int m = 0; m < 4; ++m) aF[m] = *(const bf16x8*)&Asm[m * 16 + c15][ks * 32 + kq * 8];
#pragma unroll
        for (int n = 0; n < 4; ++n) bF[n] = *(const bf16x8*)&Bsm[wv * 64 + n * 16 + c15][kq * 8];
#pragma unroll
        for (int m = 0; m < 4; ++m)
#pragma unroll
            for (int n = 0; n < 4; ++n)
                acc[m][n] = __builtin_amdgcn_mfma_f32_16x16x32_bf16(aF[m], bF[n], acc[m][n], 0, 0, 0);
    }

    const int colb = wv * 64;
    float b1c[4], w2c[4];
#pragma unroll
    for (int n = 0; n < 4; ++n) {
        int col = colb + n * 16 + c15;
        b1c[n] = b1[col];
        w2c[n] = W2[col];
    }
#pragma unroll
    for (int m = 0; m < 4; ++m) {
#pragma unroll
        for (int reg = 0; reg < 4; ++reg) {
            float s = 0.f;
#pragma unroll
            for (int n = 0; n < 4; ++n)
                s += fmaxf(acc[m][n][reg] + b1c[n], 0.f) * w2c[n];
#pragma unroll
            for (int off = 1; off < 16; off <<= 1) s += __shfl_xor(s, off, 64);
            if (c15 == 0) atomicAdd(&obuf[m * 16 + kq * 4 + reg], s);
        }
    }
    __syncthreads();
    if (tid < 64) {
        int grow = a0 + tid;
        if (grow < NA) outU[grow] = obuf[tid] + b2[0];
    }
}

// ---------------------------------------------------------------------------
// done_logits = relu(hm @ W1 + b1) @ W2 + b2  (fp32; one block per molecule)
// ---------------------------------------------------------------------------
__global__ __launch_bounds__(256) void done_kernel(
    const float* __restrict__ hm, const float* __restrict__ W1,
    const float* __restrict__ b1, const float* __restrict__ W2,
    const float* __restrict__ b2, float* __restrict__ outD, int NM)
{
    __shared__ float rsh[256];
    __shared__ float red[4];
    const int tid = threadIdx.x;
    const int mol = blockIdx.x;
    rsh[tid] = hm[(size_t)mol * 256 + tid];
    __syncthreads();
    float h0 = 0.f, h1 = 0.f;
    for (int k = 0; k < 256; ++k) {
        float rv = rsh[k];
        h0 += rv * W1[k * 512 + tid];
        h1 += rv * W1[k * 512 + tid + 256];
    }
    float part = fmaxf(h0 + b1[tid], 0.f) * W2[tid] +
                 fmaxf(h1 + b1[tid + 256], 0.f) * W2[tid + 256];
#pragma unroll
    for (int off = 1; off < 64; off <<= 1) part += __shfl_xor(part, off, 64);
    if ((tid & 63) == 0) red[tid >> 6] = part;
    __syncthreads();
    if (tid == 0) outD[mol] = red[0] + red[1] + red[2] + red[3] + b2[0];
}

// ---------------------------------------------------------------------------
extern "C" void kernel_launch(void* const* d_in, const int* in_sizes, int n_in,
                              void* d_out, int out_size, void* d_ws, size_t ws_size,
                              hipStream_t stream)
{
    const float* c_atom  = (const float*)d_in[0];
    const float* ha_prev = (const float*)d_in[1];
    const float* W_vv    = (const float*)d_in[2];
    const float* W_vc    = (const float*)d_in[3];
    const float* bW1     = (const float*)d_in[4];
    const float* bb1     = (const float*)d_in[5];
    const float* bW2     = (const float*)d_in[6];
    const float* bb2     = (const float*)d_in[7];
    const float* uW1     = (const float*)d_in[8];
    const float* ub1     = (const float*)d_in[9];
    const float* uW2     = (const float*)d_in[10];
    const float* ub2     = (const float*)d_in[11];
    const float* dW1     = (const float*)d_in[12];
    const float* db1     = (const float*)d_in[13];
    const float* dW2     = (const float*)d_in[14];
    const float* db2     = (const float*)d_in[15];
    const int* mol_id    = (const int*)d_in[16];
    const int* bidx      = (const int*)d_in[17];

    const int H = 256, BS = 5;
    const int NA = in_sizes[0] / H;
    const int NB = in_sizes[17] / 2;
    const int NM = out_size - NB * BS - NA;

    float* out  = (float*)d_out;
    float* outB = out;
    float* outU = out + (size_t)NB * BS;
    float* outD = outU + NA;

    char* ws = (char*)d_ws;
    size_t off = 0;
    unsigned short* haB = (unsigned short*)(ws + off);
    off += (size_t)NA * H * 2;            off = (off + 255) & ~(size_t)255;
    float* hm = (float*)(ws + off);
    off += (size_t)NM * H * 4;            off = (off + 255) & ~(size_t)255;
    unsigned short* WcT = (unsigned short*)(ws + off);
    off += (size_t)256 * 512 * 2;         off = (off + 255) & ~(size_t)255;
    unsigned short* bW1T = (unsigned short*)(ws + off);
    off += (size_t)512 * 512 * 2;         off = (off + 255) & ~(size_t)255;
    unsigned short* uW1T = (unsigned short*)(ws + off);

    hipMemsetAsync(hm, 0, (size_t)NM * H * 4, stream);
    conv_weights<<<2048, 256, 0, stream>>>(W_vv, W_vc, bW1, uW1, WcT, bW1T, uW1T);
    ha_kernel<<<(NA + 63) / 64, 256, 0, stream>>>(ha_prev, c_atom, WcT, mol_id, haB, hm, NA);
    bond_kernel<<<(NB + 63) / 64, 512, 0, stream>>>(haB, bidx, bW1T, bb1, bW2, bb2, outB, NB);
    uni_kernel<<<(NA + 63) / 64, 512, 0, stream>>>(haB, uW1T, ub1, uW2, ub2, outU, NA);
    done_kernel<<<NM, 256, 0, stream>>>(hm, dW1, db1, dW2, db2, outD, NM);
}